// Round 1
// 4117.385 us; speedup vs baseline: 2.1852x; 2.1852x over previous
//
#include <hip/hip_runtime.h>
#include <math.h>

#define S_TOK 4101
#define CDIM 1024
#define SKPAD_SELF 4160   // 65*64

typedef unsigned short u16;
typedef u16 us8 __attribute__((ext_vector_type(8)));
typedef u16 us4 __attribute__((ext_vector_type(4)));
typedef __bf16 bf16x8 __attribute__((ext_vector_type(8)));
typedef float f32x4 __attribute__((ext_vector_type(4)));

__device__ __forceinline__ float silu_f(float x) { return x / (1.f + expf(-x)); }
__device__ __forceinline__ float gelu_f(float x) { return 0.5f * x * (1.f + erff(x * 0.70710678118654752f)); }
__device__ __forceinline__ u16 f2b(float x) {
    unsigned u = __float_as_uint(x);
    unsigned r = (u + 0x7FFFu + ((u >> 16) & 1u)) >> 16;
    return (u16)r;
}
__device__ __forceinline__ float b2f(u16 u) { return __uint_as_float(((unsigned)u) << 16); }

// async global->LDS, 16B per lane; LDS dest is wave-uniform base + lane*16
__device__ __forceinline__ void gload16(const u16* g, u16* l) {
    __builtin_amdgcn_global_load_lds((__attribute__((address_space(1))) const void*)g,
                                     (__attribute__((address_space(3))) void*)l, 16, 0, 0);
}

// ---------------- t-freq embedding ----------------
__global__ void tfreq_kernel(const float* __restrict__ t, float* __restrict__ tf) {
    int i = threadIdx.x;
    float tv = t[0];
    int f = i & 127;
    float fr = expf(-logf(10000.f) * (float)f / 128.f);
    float a = tv * fr;
    tf[i] = (i < 128) ? cosf(a) : sinf(a);
}

__global__ void gemv_kernel(const float* __restrict__ in, const float* __restrict__ W, int ldw,
                            const float* __restrict__ bias, float* __restrict__ out,
                            int K, int N, int act) {
    int j = blockIdx.x * blockDim.x + threadIdx.x;
    if (j >= N) return;
    float acc = bias ? bias[j] : 0.f;
    for (int i = 0; i < K; ++i) acc = fmaf(in[i], W[(size_t)i * ldw + j], acc);
    if (act == 1) acc = silu_f(acc);
    out[j] = acc;
}

__global__ void silu_kernel(const float* __restrict__ in, float* __restrict__ out, int n) {
    int i = blockIdx.x * blockDim.x + threadIdx.x;
    if (i < n) out[i] = silu_f(in[i]);
}

__global__ void mod_kernel(const float* __restrict__ stemb, const float* __restrict__ ada_w,
                           const float* __restrict__ ada_b, float* __restrict__ mod) {
    int j = blockIdx.x * blockDim.x + threadIdx.x;
    if (j >= 4 * 6144) return;
    int b = j / 6144, c = j % 6144;
    const float* W = ada_w + (size_t)b * 1024 * 6144 + c;
    float acc = ada_b[j];
    for (int i = 0; i < 1024; ++i) acc = fmaf(stemb[i], W[(size_t)i * 6144], acc);
    mod[j] = acc;
}

__global__ void embed_kernel(const float* __restrict__ x, const float* __restrict__ in_w,
                             const float* __restrict__ in_b, const float* __restrict__ pos_token,
                             const float* __restrict__ reg_token, float* __restrict__ h) {
    int id = blockIdx.x * 256 + threadIdx.x;
    if (id >= S_TOK * CDIM) return;
    int row = id >> 10, c = id & 1023;
    float v;
    if (row == 0) v = pos_token[c];
    else if (row < 5) v = reg_token[(row - 1) * 1024 + c];
    else {
        int l = row - 5;
        float acc = in_b[c];
#pragma unroll
        for (int ch = 0; ch < 8; ++ch) acc = fmaf(x[ch * 4096 + l], in_w[ch * 1024 + c], acc);
        float pe = 0.f;
        if (c < 1020) {
            int coordIdx = c / 340, r2 = c % 340;
            int coord;
            if (coordIdx == 0) coord = l >> 8;
            else if (coordIdx == 1) coord = (l >> 4) & 15;
            else coord = l & 15;
            int f = (r2 < 170) ? r2 : r2 - 170;
            float fr = expf(-logf(10000.f) * (float)f / 170.f);
            float a = (float)coord * fr;
            pe = (r2 < 170) ? sinf(a) : cosf(a);
        }
        v = acc + pe;
    }
    h[id] = v;
}

// ---------------- LayerNorm (fp32 in, bf16 out): mode 0 plain, 1: *(1+w)+b, 2: *w+b
__global__ __launch_bounds__(256) void ln_kernel(const float* __restrict__ X, u16* __restrict__ Y,
                                                 const float* __restrict__ w, const float* __restrict__ b,
                                                 int mode) {
    int row = blockIdx.x;
    const float* x = X + (size_t)row * CDIM;
    float4 v = ((const float4*)x)[threadIdx.x];
    float s = v.x + v.y + v.z + v.w;
    float ss = v.x * v.x + v.y * v.y + v.z * v.z + v.w * v.w;
#pragma unroll
    for (int o = 32; o > 0; o >>= 1) { s += __shfl_xor(s, o); ss += __shfl_xor(ss, o); }
    __shared__ float sa[4], sb[4];
    int wv = threadIdx.x >> 6;
    if ((threadIdx.x & 63) == 0) { sa[wv] = s; sb[wv] = ss; }
    __syncthreads();
    s = sa[0] + sa[1] + sa[2] + sa[3];
    ss = sb[0] + sb[1] + sb[2] + sb[3];
    float mean = s * (1.f / 1024.f);
    float var = ss * (1.f / 1024.f) - mean * mean;
    float r = rsqrtf(var + 1e-6f);
    int c = threadIdx.x << 2;
    float t0 = (v.x - mean) * r, t1 = (v.y - mean) * r, t2 = (v.z - mean) * r, t3 = (v.w - mean) * r;
    float o0, o1, o2, o3;
    if (mode == 0) { o0 = t0; o1 = t1; o2 = t2; o3 = t3; }
    else if (mode == 1) {
        o0 = t0 * (1.f + w[c]) + b[c];
        o1 = t1 * (1.f + w[c + 1]) + b[c + 1];
        o2 = t2 * (1.f + w[c + 2]) + b[c + 2];
        o3 = t3 * (1.f + w[c + 3]) + b[c + 3];
    } else {
        o0 = t0 * w[c] + b[c];
        o1 = t1 * w[c + 1] + b[c + 1];
        o2 = t2 * w[c + 2] + b[c + 2];
        o3 = t3 * w[c + 3] + b[c + 3];
    }
    union { u16 u[4]; us4 v4; } pk;
    pk.u[0] = f2b(o0); pk.u[1] = f2b(o1); pk.u[2] = f2b(o2); pk.u[3] = f2b(o3);
    ((us4*)(Y + (size_t)row * CDIM))[threadIdx.x] = pk.v4;
}

// ---------------- weight transpose + fp32->bf16: W[K][N] -> Wt[N][K] ----------------
__global__ __launch_bounds__(256) void wtrans_kernel(const float* __restrict__ W, u16* __restrict__ Wt,
                                                     int K, int N) {
    __shared__ u16 s[64 * 72];
    int n0 = blockIdx.x * 64, k0 = blockIdx.y * 64;
    int t = threadIdx.x;
    int kk = t >> 4, n4 = (t & 15) * 4;
#pragma unroll
    for (int i = 0; i < 4; ++i) {
        int k = kk + i * 16;
        float4 w4 = *(const float4*)(W + (size_t)(k0 + k) * N + n0 + n4);
        s[(n4 + 0) * 72 + k] = f2b(w4.x);
        s[(n4 + 1) * 72 + k] = f2b(w4.y);
        s[(n4 + 2) * 72 + k] = f2b(w4.z);
        s[(n4 + 3) * 72 + k] = f2b(w4.w);
    }
    __syncthreads();
    int n = t >> 2, kh = (t & 3) * 16;
    u16* dst = Wt + (size_t)(n0 + n) * K + k0 + kh;
    *(us8*)dst = *(const us8*)&s[n * 72 + kh];
    *(us8*)(dst + 8) = *(const us8*)&s[n * 72 + kh + 8];
}

// fp32 -> bf16 elementwise
__global__ void cvt_kernel(const float* __restrict__ src, u16* __restrict__ dst, int n) {
    int i = blockIdx.x * 256 + threadIdx.x;
    if (i < n) dst[i] = f2b(src[i]);
}

// ---------------- bf16 MFMA GEMM: C[M,N] = A[M,K] @ B[K,N](as Bt[N][K]) + bias ----------------
__global__ __launch_bounds__(256) void bgemm_kernel(const u16* __restrict__ A, int lda,
                                                    const u16* __restrict__ Bt, int ldbt,
                                                    float* __restrict__ C, u16* __restrict__ Cb, int ldc,
                                                    int M, int N, int K,
                                                    const float* __restrict__ bias, int act) {
    __shared__ u16 As[128 * 40];
    __shared__ u16 Bs[128 * 40];
    int t = threadIdx.x;
    int w = t >> 6, lane = t & 63, quad = lane >> 4, l15 = lane & 15;
    int wm = w & 1, wn = w >> 1;
    int m0 = blockIdx.y * 128, n0 = blockIdx.x * 128;
    int sr = t >> 1, skh = (t & 1) * 16;
    int arow = m0 + sr; if (arow >= M) arow = M - 1;
    const u16* ap = A + (size_t)arow * lda + skh;
    const u16* bp = Bt + (size_t)(n0 + sr) * ldbt + skh;
    u16* asw = &As[sr * 40 + skh];
    u16* bsw = &Bs[sr * 40 + skh];
    f32x4 acc[4][4];
#pragma unroll
    for (int i = 0; i < 4; ++i)
#pragma unroll
        for (int j = 0; j < 4; ++j) acc[i][j] = (f32x4){0.f, 0.f, 0.f, 0.f};
    const u16* ar = &As[(wm * 64 + l15) * 40 + quad * 8];
    const u16* br = &Bs[(wn * 64 + l15) * 40 + quad * 8];
    for (int k0 = 0; k0 < K; k0 += 32) {
        us8 a0 = *(const us8*)(ap + k0);
        us8 a1 = *(const us8*)(ap + k0 + 8);
        us8 b0 = *(const us8*)(bp + k0);
        us8 b1 = *(const us8*)(bp + k0 + 8);
        *(us8*)asw = a0; *(us8*)(asw + 8) = a1;
        *(us8*)bsw = b0; *(us8*)(bsw + 8) = b1;
        __syncthreads();
        bf16x8 af[4], bfr[4];
#pragma unroll
        for (int mt = 0; mt < 4; ++mt) af[mt] = *(const bf16x8*)(ar + mt * 16 * 40);
#pragma unroll
        for (int nt = 0; nt < 4; ++nt) bfr[nt] = *(const bf16x8*)(br + nt * 16 * 40);
#pragma unroll
        for (int mt = 0; mt < 4; ++mt)
#pragma unroll
            for (int nt = 0; nt < 4; ++nt)
                acc[mt][nt] = __builtin_amdgcn_mfma_f32_16x16x32_bf16(af[mt], bfr[nt], acc[mt][nt], 0, 0, 0);
        __syncthreads();
    }
#pragma unroll
    for (int nt = 0; nt < 4; ++nt) {
        int ncol = n0 + wn * 64 + nt * 16 + l15;
        float bv = bias[ncol];
#pragma unroll
        for (int mt = 0; mt < 4; ++mt) {
#pragma unroll
            for (int r = 0; r < 4; ++r) {
                int row = m0 + wm * 64 + mt * 16 + quad * 4 + r;
                if (row < M) {
                    float v = acc[mt][nt][r] + bv;
                    if (act) v = gelu_f(v);
                    if (Cb) Cb[(size_t)row * ldc + ncol] = f2b(v);
                    else C[(size_t)row * ldc + ncol] = v;
                }
            }
        }
    }
}

// ---------------- RMS-norm * gamma on q slice of qkv buffer (fp32, in place) ----------------
__global__ void rmsq_kernel(float* __restrict__ qkv, const float* __restrict__ qg, int S) {
    int gid = blockIdx.x * blockDim.x + threadIdx.x;
    int wid = gid >> 6;
    int lane = gid & 63;
    if (wid >= S * 16) return;
    int s = wid >> 4, hh = wid & 15;
    float* p = qkv + (size_t)s * 3072 + hh * 64 + lane;
    float v = *p;
    float sq = v * v;
#pragma unroll
    for (int o = 32; o > 0; o >>= 1) sq += __shfl_xor(sq, o);
    float r = rsqrtf(sq * (1.f / 64.f) + 1e-6f);
    *p = v * r * qg[hh * 64 + lane];
}

// ---------------- K prep: fp32 rows (stride ld) -> bf16 Kb[h][Skpad][64], optional rms*gamma
__global__ void kprep_kernel(const float* __restrict__ K, int ld, u16* __restrict__ Kb,
                             int Sk, int Skpad, const float* __restrict__ gamma) {
    int v = threadIdx.x >> 6, lane = threadIdx.x & 63;
    int s = blockIdx.x * 4 + v;
    int h = blockIdx.y;
    if (s >= Skpad) return;
    u16* dst = Kb + ((size_t)h * Skpad + s) * 64 + lane;
    if (s >= Sk) { *dst = 0; return; }
    float x = K[(size_t)s * ld + h * 64 + lane];
    if (gamma) {
        float sq = x * x;
#pragma unroll
        for (int o = 32; o > 0; o >>= 1) sq += __shfl_xor(sq, o);
        x = x * rsqrtf(sq * (1.f / 64.f) + 1e-6f) * gamma[h * 64 + lane];
    }
    *dst = f2b(x);
}

// ---------------- V prep: transpose per head -> bf16 Vt[h][64][Skpad]
__global__ __launch_bounds__(256) void vtprep_kernel(const float* __restrict__ V, int ld,
                                                     u16* __restrict__ Vt, int Sk, int Skpad) {
    __shared__ __align__(16) u16 s[64 * 72];
    int h = blockIdx.y;
    int k0 = blockIdx.x * 64;
    int t = threadIdx.x;
    int kk = t >> 4, d4 = (t & 15) * 4;
#pragma unroll
    for (int i = 0; i < 4; ++i) {
        int k = kk + i * 16;
        float4 v4 = make_float4(0.f, 0.f, 0.f, 0.f);
        if (k0 + k < Sk) v4 = *(const float4*)(V + (size_t)(k0 + k) * ld + h * 64 + d4);
        s[(d4 + 0) * 72 + k] = f2b(v4.x);
        s[(d4 + 1) * 72 + k] = f2b(v4.y);
        s[(d4 + 2) * 72 + k] = f2b(v4.z);
        s[(d4 + 3) * 72 + k] = f2b(v4.w);
    }
    __syncthreads();
    int d = t >> 2, kh = (t & 3) * 16;
    u16* dst = Vt + ((size_t)h * 64 + d) * Skpad + k0 + kh;
    *(us8*)dst = *(const us8*)&s[d * 72 + kh];
    *(us8*)(dst + 8) = *(const us8*)&s[d * 72 + kh + 8];
}

// ---------------- MFMA flash attention v2 ----------------
// Pre-converted bf16 K (Kb[h][Skpad][64]) and V^T (Vt[h][64][Skpad]).
// Double-buffered global_load_lds staging (XOR-swizzled 16B chunks, linear LDS
// dest, swizzled source), raw s_barrier + counted vmcnt so next-tile loads fly
// under current tile's compute. 4 waves x 16 q each, K-tile 64.
__global__ __launch_bounds__(256) void attn2_kernel(const float* __restrict__ Q, int qs,
                                                    const u16* __restrict__ Kb,
                                                    const u16* __restrict__ Vt,
                                                    int Skpad,
                                                    u16* __restrict__ O, int os,
                                                    int Sq, int Sk, int nqb) {
    __shared__ __align__(16) u16 sK2[2][64 * 64];
    __shared__ __align__(16) u16 sV2[2][64 * 64];
    __shared__ __align__(16) u16 sP[64 * 64];
    // XCD-aware bijective swizzle: consecutive gid share head -> same-XCD L2 reuse
    int nwg = nqb * 16;
    int cpx = nwg >> 3;                       // nwg % 8 == 0
    int bid = blockIdx.x;
    int gid = (bid & 7) * cpx + (bid >> 3);
    int hh = gid / nqb;
    int q0 = (gid - hh * nqb) * 64;
    int t = threadIdx.x;
    int w = t >> 6, lane = t & 63, quad = lane >> 4, l15 = lane & 15;
    const u16* KH = Kb + (size_t)hh * Skpad * 64;
    const u16* VH = Vt + (size_t)hh * 64 * Skpad;
    // Q fragments, scaled by 1/8 (B-operand of S^T = K.Q^T)
    int qrow = q0 + w * 16 + l15; if (qrow >= Sq) qrow = Sq - 1;
    const float* qp = Q + (size_t)qrow * qs + hh * 64 + quad * 8;
    bf16x8 bq[2];
#pragma unroll
    for (int c = 0; c < 2; ++c) {
        float4 x = *(const float4*)(qp + c * 32);
        float4 y = *(const float4*)(qp + c * 32 + 4);
        union { u16 u[8]; bf16x8 v; } pk;
        pk.u[0] = f2b(x.x * 0.125f); pk.u[1] = f2b(x.y * 0.125f);
        pk.u[2] = f2b(x.z * 0.125f); pk.u[3] = f2b(x.w * 0.125f);
        pk.u[4] = f2b(y.x * 0.125f); pk.u[5] = f2b(y.y * 0.125f);
        pk.u[6] = f2b(y.z * 0.125f); pk.u[7] = f2b(y.w * 0.125f);
        bq[c] = pk.v;
    }
    float m_run = -3e38f, l_run = 0.f;
    f32x4 oacc[4];
#pragma unroll
    for (int j = 0; j < 4; ++j) oacc[j] = (f32x4){0.f, 0.f, 0.f, 0.f};

    // staging geometry: tile = 64 rows x 8 chunks(16B). thread covers chunk t and 256+t.
    // LDS slot (r,c) holds global chunk (r, c ^ (r&7)) -> conflict-free b128 reads.
    int r0 = t >> 3;
    int c0 = (t & 7) ^ (r0 & 7);              // same for round 1 since (r0+32)&7 == r0&7
    int ldsc = (t & 192) << 3;                // wave-uniform dest base (u16), + lane*8 by HW

    auto STAGE = [&](u16* skb, u16* svb, int k0) {
        const u16* gk0 = KH + ((size_t)(k0 + r0) << 6) + (c0 << 3);
        const u16* gk1 = KH + ((size_t)(k0 + r0 + 32) << 6) + (c0 << 3);
        const u16* gv0 = VH + (size_t)r0 * Skpad + k0 + (c0 << 3);
        const u16* gv1 = VH + (size_t)(r0 + 32) * Skpad + k0 + (c0 << 3);
        gload16(gk0, skb + ldsc);
        gload16(gv0, svb + ldsc);
        gload16(gk1, skb + 2048 + ldsc);
        gload16(gv1, svb + 2048 + ldsc);
    };

    int ntile = Skpad >> 6;
    STAGE(sK2[0], sV2[0], 0);
    for (int tt = 0; tt < ntile; ++tt) {
        int k0 = tt << 6;
        int b = tt & 1;
        if (tt + 1 < ntile) {
            STAGE(sK2[b ^ 1], sV2[b ^ 1], k0 + 64);
            asm volatile("s_waitcnt vmcnt(4)" ::: "memory");   // tile tt landed; tt+1 in flight
        } else {
            asm volatile("s_waitcnt vmcnt(0)" ::: "memory");
        }
        __builtin_amdgcn_s_barrier();
        const u16* sk = sK2[b];
        const u16* sv = sV2[b];
        // scores S^T[key][q]
        f32x4 sc[4];
#pragma unroll
        for (int mt = 0; mt < 4; ++mt) {
            int row = mt * 16 + l15;
            int sw = row & 7;
            bf16x8 a0 = *(const bf16x8*)(sk + (((row << 3) | (quad ^ sw)) << 3));
            bf16x8 a1 = *(const bf16x8*)(sk + (((row << 3) | ((4 | quad) ^ sw)) << 3));
            f32x4 z = (f32x4){0.f, 0.f, 0.f, 0.f};
            z = __builtin_amdgcn_mfma_f32_16x16x32_bf16(a0, bq[0], z, 0, 0, 0);
            z = __builtin_amdgcn_mfma_f32_16x16x32_bf16(a1, bq[1], z, 0, 0, 0);
            sc[mt] = z;
        }
        // mask invalid keys (tail tile only; padded K rows are zero-filled)
        if (k0 + 64 > Sk) {
#pragma unroll
            for (int mt = 0; mt < 4; ++mt)
#pragma unroll
                for (int r = 0; r < 4; ++r)
                    if (k0 + mt * 16 + quad * 4 + r >= Sk) sc[mt][r] = -3e38f;
        }
        // online softmax per q (= l15 column), reduce across quads
        float mx = -3e38f;
#pragma unroll
        for (int mt = 0; mt < 4; ++mt)
#pragma unroll
            for (int r = 0; r < 4; ++r) mx = fmaxf(mx, sc[mt][r]);
        mx = fmaxf(mx, __shfl_xor(mx, 16));
        mx = fmaxf(mx, __shfl_xor(mx, 32));
        float mn = fmaxf(m_run, mx);
        float alpha = __expf(m_run - mn);
        float ls = 0.f;
#pragma unroll
        for (int mt = 0; mt < 4; ++mt)
#pragma unroll
            for (int r = 0; r < 4; ++r) {
                float p = __expf(sc[mt][r] - mn);
                sc[mt][r] = p;
                ls += p;
            }
        ls += __shfl_xor(ls, 16);
        ls += __shfl_xor(ls, 32);
        l_run = l_run * alpha + ls;
        m_run = mn;
        // write P rows (q-major, chunk-XOR-swizzled) as bf16
#pragma unroll
        for (int mt = 0; mt < 4; ++mt) {
            union { u16 u[4]; us4 v; } pk;
            pk.u[0] = f2b(sc[mt][0]); pk.u[1] = f2b(sc[mt][1]);
            pk.u[2] = f2b(sc[mt][2]); pk.u[3] = f2b(sc[mt][3]);
            int pch = (mt * 2 + (quad >> 1)) ^ (l15 & 7);
            *(us4*)&sP[(w * 16 + l15) * 64 + pch * 8 + (quad & 1) * 4] = pk.v;
        }
        // rescale O by alpha of each output row q' = quad*4+r
        float alr[4];
#pragma unroll
        for (int r = 0; r < 4; ++r) alr[r] = __shfl(alpha, (lane & 48) | (quad * 4 + r));
#pragma unroll
        for (int j = 0; j < 4; ++j)
#pragma unroll
            for (int r = 0; r < 4; ++r) oacc[j][r] *= alr[r];
        // PV
#pragma unroll
        for (int c = 0; c < 2; ++c) {
            bf16x8 pa = *(const bf16x8*)&sP[(w * 16 + l15) * 64 + ((((c << 2) | quad) ^ (l15 & 7)) << 3)];
#pragma unroll
            for (int n2 = 0; n2 < 4; ++n2) {
                int row = n2 * 16 + l15;
                int ch = ((c << 2) | quad) ^ (row & 7);
                bf16x8 vb = *(const bf16x8*)(sv + (((row << 3) | ch) << 3));
                oacc[n2] = __builtin_amdgcn_mfma_f32_16x16x32_bf16(pa, vb, oacc[n2], 0, 0, 0);
            }
        }
        __builtin_amdgcn_s_barrier();   // all reads of buf b done before it is restaged
        asm volatile("" ::: "memory");
    }
    float lr[4];
#pragma unroll
    for (int r = 0; r < 4; ++r) lr[r] = __shfl(l_run, (lane & 48) | (quad * 4 + r));
#pragma unroll
    for (int r = 0; r < 4; ++r) {
        int q = q0 + w * 16 + quad * 4 + r;
        if (q < Sq) {
            float inv = 1.f / lr[r];
#pragma unroll
            for (int j = 0; j < 4; ++j)
                O[(size_t)q * os + hh * 64 + j * 16 + l15] = f2b(oacc[j][r] * inv);
        }
    }
}

// h += (g ? g[c]* : 1*) p
__global__ void resid_kernel(float* __restrict__ h, const float* __restrict__ p,
                             const float* __restrict__ g, int n4) {
    int i = blockIdx.x * 256 + threadIdx.x;
    if (i >= n4) return;
    float4 hv = ((float4*)h)[i];
    float4 pv = ((const float4*)p)[i];
    if (g) {
        int c = (i & 255) << 2;
        hv.x += g[c] * pv.x;
        hv.y += g[c + 1] * pv.y;
        hv.z += g[c + 2] * pv.z;
        hv.w += g[c + 3] * pv.w;
    } else {
        hv.x += pv.x; hv.y += pv.y; hv.z += pv.z; hv.w += pv.w;
    }
    ((float4*)h)[i] = hv;
}

// out[c][l] = hn_bf16[5+l] . out_w[:,c] + out_b[c]
__global__ void out_kernel(const u16* __restrict__ hn, const float* __restrict__ out_w,
                           const float* __restrict__ out_b, float* __restrict__ out) {
    int id = blockIdx.x * 256 + threadIdx.x;
    if (id >= 4096 * 8) return;
    int l = id >> 3, c = id & 7;
    const u16* row = hn + (size_t)(5 + l) * CDIM;
    float acc = out_b[c];
    for (int k = 0; k < 1024; ++k) acc = fmaf(b2f(row[k]), out_w[k * 8 + c], acc);
    out[c * 4096 + l] = acc;
}

extern "C" void kernel_launch(void* const* d_in, const int* in_sizes, int n_in,
                              void* d_out, int out_size, void* d_ws, size_t ws_size,
                              hipStream_t stream) {
    const float* x        = (const float*)d_in[0];
    const float* t        = (const float*)d_in[1];
    const float* cond     = (const float*)d_in[2];
    const float* t_w1     = (const float*)d_in[3];
    const float* t_b1     = (const float*)d_in[4];
    const float* t_w2     = (const float*)d_in[5];
    const float* t_b2     = (const float*)d_in[6];
    const float* in_w     = (const float*)d_in[7];
    const float* in_b     = (const float*)d_in[8];
    const float* pos_tok  = (const float*)d_in[9];
    const float* reg_tok  = (const float*)d_in[10];
    const float* ada_w    = (const float*)d_in[11];
    const float* ada_b    = (const float*)d_in[12];
    const float* qkv_w    = (const float*)d_in[13];
    const float* qkv_b    = (const float*)d_in[14];
    const float* q_gamma  = (const float*)d_in[15];
    const float* k_gamma  = (const float*)d_in[16];
    const float* attn_ow  = (const float*)d_in[17];
    const float* attn_ob  = (const float*)d_in[18];
    const float* n2_w     = (const float*)d_in[19];
    const float* n2_b     = (const float*)d_in[20];
    const float* cq_w     = (const float*)d_in[21];
    const float* cq_b     = (const float*)d_in[22];
    const float* ckv_w    = (const float*)d_in[23];
    const float* ckv_b    = (const float*)d_in[24];
    const float* co_w     = (const float*)d_in[25];
    const float* co_b     = (const float*)d_in[26];
    const float* mlp_w1   = (const float*)d_in[27];
    const float* mlp_b1   = (const float*)d_in[28];
    const float* mlp_w2   = (const float*)d_in[29];
    const float* mlp_b2   = (const float*)d_in[30];
    const float* out_w    = (const float*)d_in[31];
    const float* out_b    = (const float*)d_in[32];

    const int S = S_TOK;
    const size_t SC = (size_t)S * 1024;
    float* ws = (float*)d_ws;
    float* h    = ws;                    // S*1024 fp32
    float* F    = h + SC;                // S*1024 fp32
    float* D    = F + SC;                // S*4096 fp32 (also: q | kv | ff1-bf16)
    float* tf   = D + SC * 4;
    float* s1   = tf + 256;
    float* temb = s1 + 1024;
    float* stemb = temb + 1024;
    float* mod  = stemb + 1024;          // 4*6144
    float* fend = mod + 4 * 6144;
    u16* hn    = (u16*)fend;             // S*1024 bf16
    u16* E     = hn + SC;                // S*1024 bf16
    u16* condb = E + SC;                 // 1M bf16
    u16* wt    = condb + 1024 * 1024;
    u16* wt_qkv = wt;
    u16* wt_o   = wt_qkv + (size_t)1024 * 3072;
    u16* wt_cq  = wt_o   + (size_t)1024 * 1024;
    u16* wt_ckv = wt_cq  + (size_t)1024 * 1024;
    u16* wt_co  = wt_ckv + (size_t)1024 * 2048;
    u16* wt_m1  = wt_co  + (size_t)1024 * 1024;
    u16* wt_m2  = wt_m1  + (size_t)1024 * 4096;
    u16* Kb     = wt_m2  + (size_t)4096 * 1024;          // 16*4160*64 bf16
    u16* Vt     = Kb + (size_t)16 * SKPAD_SELF * 64;     // 16*4160*64 bf16
    float* q_buf = D;                    // cross-attn q (S*1024 fp32)
    float* kv    = D + SC;               // 1024*2048 fp32
    u16* ff1     = (u16*)D;              // S*4096 bf16

    // temb / adaLN modulation chain
    tfreq_kernel<<<1, 256, 0, stream>>>(t, tf);
    gemv_kernel<<<4, 256, 0, stream>>>(tf, t_w1, 1024, t_b1, s1, 256, 1024, 1);
    gemv_kernel<<<4, 256, 0, stream>>>(s1, t_w2, 1024, t_b2, temb, 1024, 1024, 0);
    silu_kernel<<<4, 256, 0, stream>>>(temb, stemb, 1024);
    mod_kernel<<<96, 256, 0, stream>>>(stemb, ada_w, ada_b, mod);

    // input embed + cond bf16
    embed_kernel<<<(S * 1024 + 255) / 256, 256, 0, stream>>>(x, in_w, in_b, pos_tok, reg_tok, h);
    cvt_kernel<<<4096, 256, 0, stream>>>(cond, condb, 1024 * 1024);

    int gy = (S + 127) / 128;   // 33
    int nqb = (S + 63) / 64;    // 65
    int nwg = nqb * 16;         // 1040 (divisible by 8)
    for (int i = 0; i < 4; ++i) {
        const float* modb = mod + i * 6144;
        // weight prep (transpose + bf16)
        wtrans_kernel<<<dim3(3072 / 64, 16), 256, 0, stream>>>(qkv_w + (size_t)i * 1024 * 3072, wt_qkv, 1024, 3072);
        wtrans_kernel<<<dim3(16, 16), 256, 0, stream>>>(attn_ow + (size_t)i * 1024 * 1024, wt_o, 1024, 1024);
        wtrans_kernel<<<dim3(16, 16), 256, 0, stream>>>(cq_w + (size_t)i * 1024 * 1024, wt_cq, 1024, 1024);
        wtrans_kernel<<<dim3(32, 16), 256, 0, stream>>>(ckv_w + (size_t)i * 1024 * 2048, wt_ckv, 1024, 2048);
        wtrans_kernel<<<dim3(16, 16), 256, 0, stream>>>(co_w + (size_t)i * 1024 * 1024, wt_co, 1024, 1024);
        wtrans_kernel<<<dim3(64, 16), 256, 0, stream>>>(mlp_w1 + (size_t)i * 1024 * 4096, wt_m1, 1024, 4096);
        wtrans_kernel<<<dim3(16, 64), 256, 0, stream>>>(mlp_w2 + (size_t)i * 4096 * 1024, wt_m2, 4096, 1024);

        // hn = ln(h)*(1+sc1)+sh1  (bf16)
        ln_kernel<<<S, 256, 0, stream>>>(h, hn, modb + 1024, modb + 0, 1);
        // qkv = hn @ qkv_w + b  (fp32 out)
        bgemm_kernel<<<dim3(24, gy), 256, 0, stream>>>(hn, 1024, wt_qkv, 1024, D, nullptr, 3072,
                                                       S, 3072, 1024, qkv_b + i * 3072, 0);
        // q-rms in place; k-rms fused into kprep; V transposed once per layer
        rmsq_kernel<<<(S * 16 * 64 + 255) / 256, 256, 0, stream>>>(D, q_gamma + i * 1024, S);
        kprep_kernel<<<dim3(SKPAD_SELF / 4, 16), 256, 0, stream>>>(D + 1024, 3072, Kb, S, SKPAD_SELF, k_gamma + i * 1024);
        vtprep_kernel<<<dim3(SKPAD_SELF / 64, 16), 256, 0, stream>>>(D + 2048, 3072, Vt, S, SKPAD_SELF);
        // self attention -> E (bf16)
        attn2_kernel<<<nwg, 256, 0, stream>>>(D, 3072, Kb, Vt, SKPAD_SELF, E, 1024, S, S, nqb);
        // o-proj
        bgemm_kernel<<<dim3(8, gy), 256, 0, stream>>>(E, 1024, wt_o, 1024, F, nullptr, 1024,
                                                      S, 1024, 1024, attn_ob + i * 1024, 0);
        resid_kernel<<<S, 256, 0, stream>>>(h, F, modb + 2 * 1024, S * 256);

        // hn = ln(h, n2_w, n2_b)
        ln_kernel<<<S, 256, 0, stream>>>(h, hn, n2_w + i * 1024, n2_b + i * 1024, 2);
        // q = hn @ cq_w
        bgemm_kernel<<<dim3(8, gy), 256, 0, stream>>>(hn, 1024, wt_cq, 1024, q_buf, nullptr, 1024,
                                                      S, 1024, 1024, cq_b + i * 1024, 0);
        // kv = cond @ ckv_w
        bgemm_kernel<<<dim3(16, 8), 256, 0, stream>>>(condb, 1024, wt_ckv, 1024, kv, nullptr, 2048,
                                                      1024, 2048, 1024, ckv_b + i * 2048, 0);
        // cross-attn prep (no rms) + attention -> E
        kprep_kernel<<<dim3(1024 / 4, 16), 256, 0, stream>>>(kv, 2048, Kb, 1024, 1024, nullptr);
        vtprep_kernel<<<dim3(1024 / 64, 16), 256, 0, stream>>>(kv + 1024, 2048, Vt, 1024, 1024);
        attn2_kernel<<<nwg, 256, 0, stream>>>(q_buf, 1024, Kb, Vt, 1024, E, 1024, S, 1024, nqb);
        // co proj
        bgemm_kernel<<<dim3(8, gy), 256, 0, stream>>>(E, 1024, wt_co, 1024, F, nullptr, 1024,
                                                      S, 1024, 1024, co_b + i * 1024, 0);
        resid_kernel<<<S, 256, 0, stream>>>(h, F, nullptr, S * 256);

        // hn = ln(h)*(1+sc2)+sh2
        ln_kernel<<<S, 256, 0, stream>>>(h, hn, modb + 4 * 1024, modb + 3 * 1024, 1);
        // ff1 = gelu(hn @ mlp_w1 + b1)  (bf16 out)
        bgemm_kernel<<<dim3(32, gy), 256, 0, stream>>>(hn, 1024, wt_m1, 1024, nullptr, ff1, 4096,
                                                       S, 4096, 1024, mlp_b1 + i * 4096, 1);
        // ff2 = ff1 @ mlp_w2 + b2
        bgemm_kernel<<<dim3(8, gy), 256, 0, stream>>>(ff1, 4096, wt_m2, 4096, F, nullptr, 1024,
                                                      S, 1024, 4096, mlp_b2 + i * 1024, 0);
        resid_kernel<<<S, 256, 0, stream>>>(h, F, modb + 5 * 1024, S * 256);
    }
    // final LN + out proj + transpose
    ln_kernel<<<S, 256, 0, stream>>>(h, hn, nullptr, nullptr, 0);
    out_kernel<<<128, 256, 0, stream>>>(hn, out_w, out_b, (float*)d_out);
}

// Round 2
// 3235.442 us; speedup vs baseline: 2.7809x; 1.2726x over previous
//
#include <hip/hip_runtime.h>
#include <math.h>

#define S_TOK 4101
#define CDIM 1024
#define SKPAD_SELF 4160   // 65*64

typedef unsigned short u16;
typedef u16 us8 __attribute__((ext_vector_type(8)));
typedef u16 us4 __attribute__((ext_vector_type(4)));
typedef __bf16 bf16x8 __attribute__((ext_vector_type(8)));
typedef float f32x4 __attribute__((ext_vector_type(4)));

__device__ __forceinline__ float silu_f(float x) { return x / (1.f + expf(-x)); }
__device__ __forceinline__ float gelu_f(float x) { return 0.5f * x * (1.f + erff(x * 0.70710678118654752f)); }
__device__ __forceinline__ u16 f2b(float x) {
    unsigned u = __float_as_uint(x);
    unsigned r = (u + 0x7FFFu + ((u >> 16) & 1u)) >> 16;
    return (u16)r;
}
__device__ __forceinline__ float b2f(u16 u) { return __uint_as_float(((unsigned)u) << 16); }

// async global->LDS, 16B per lane; LDS dest is wave-uniform base + lane*16
__device__ __forceinline__ void gload16(const u16* g, u16* l) {
    __builtin_amdgcn_global_load_lds((__attribute__((address_space(1))) const void*)g,
                                     (__attribute__((address_space(3))) void*)l, 16, 0, 0);
}

// ---------------- t-freq embedding ----------------
__global__ void tfreq_kernel(const float* __restrict__ t, float* __restrict__ tf) {
    int i = threadIdx.x;
    float tv = t[0];
    int f = i & 127;
    float fr = expf(-logf(10000.f) * (float)f / 128.f);
    float a = tv * fr;
    tf[i] = (i < 128) ? cosf(a) : sinf(a);
}

// ---------------- GEMV split-K: partial over K-chunk, then reduce ----------------
__global__ void gemvp_kernel(const float* __restrict__ in, const float* __restrict__ W, int ldw,
                             float* __restrict__ part, int klen, int N) {
    int j = blockIdx.x * 256 + threadIdx.x;
    if (j >= N) return;
    int k0 = blockIdx.y * klen;
    const float* Wp = W + (size_t)k0 * ldw + j;
    float acc = 0.f;
    for (int i = 0; i < klen; ++i) acc = fmaf(in[k0 + i], Wp[(size_t)i * ldw], acc);
    part[(size_t)blockIdx.y * N + j] = acc;
}

__global__ void gemvr_kernel(const float* __restrict__ part, const float* __restrict__ bias,
                             float* __restrict__ out, int N, int kc, int act) {
    int j = blockIdx.x * 256 + threadIdx.x;
    if (j >= N) return;
    float acc = bias[j];
    for (int c = 0; c < kc; ++c) acc += part[(size_t)c * N + j];
    if (act == 1) acc = silu_f(acc);
    out[j] = acc;
}

// ---------------- adaLN modulation, split-K ----------------
__global__ void modp_kernel(const float* __restrict__ stemb, const float* __restrict__ ada_w,
                            float* __restrict__ part) {
    int j = blockIdx.x * 256 + threadIdx.x;   // < 24576
    int b = j / 6144, c = j % 6144;
    int k0 = blockIdx.y * 64;
    const float* Wp = ada_w + (size_t)b * 1024 * 6144 + (size_t)k0 * 6144 + c;
    float acc = 0.f;
#pragma unroll 4
    for (int i = 0; i < 64; ++i) acc = fmaf(stemb[k0 + i], Wp[(size_t)i * 6144], acc);
    part[(size_t)blockIdx.y * 24576 + j] = acc;
}

__global__ void modr_kernel(const float* __restrict__ part, const float* __restrict__ ada_b,
                            float* __restrict__ mod) {
    int j = blockIdx.x * 256 + threadIdx.x;
    float acc = ada_b[j];
#pragma unroll
    for (int c = 0; c < 16; ++c) acc += part[(size_t)c * 24576 + j];
    mod[j] = acc;
}

__global__ void embed_kernel(const float* __restrict__ x, const float* __restrict__ in_w,
                             const float* __restrict__ in_b, const float* __restrict__ pos_token,
                             const float* __restrict__ reg_token, float* __restrict__ h) {
    int id = blockIdx.x * 256 + threadIdx.x;
    if (id >= S_TOK * CDIM) return;
    int row = id >> 10, c = id & 1023;
    float v;
    if (row == 0) v = pos_token[c];
    else if (row < 5) v = reg_token[(row - 1) * 1024 + c];
    else {
        int l = row - 5;
        float acc = in_b[c];
#pragma unroll
        for (int ch = 0; ch < 8; ++ch) acc = fmaf(x[ch * 4096 + l], in_w[ch * 1024 + c], acc);
        float pe = 0.f;
        if (c < 1020) {
            int coordIdx = c / 340, r2 = c % 340;
            int coord;
            if (coordIdx == 0) coord = l >> 8;
            else if (coordIdx == 1) coord = (l >> 4) & 15;
            else coord = l & 15;
            int f = (r2 < 170) ? r2 : r2 - 170;
            float fr = expf(-logf(10000.f) * (float)f / 170.f);
            float a = (float)coord * fr;
            pe = (r2 < 170) ? sinf(a) : cosf(a);
        }
        v = acc + pe;
    }
    h[id] = v;
}

// ---------------- LayerNorm (fp32 in, bf16 out): mode 0 plain, 1: *(1+w)+b, 2: *w+b
__global__ __launch_bounds__(256) void ln_kernel(const float* __restrict__ X, u16* __restrict__ Y,
                                                 const float* __restrict__ w, const float* __restrict__ b,
                                                 int mode) {
    int row = blockIdx.x;
    const float* x = X + (size_t)row * CDIM;
    float4 v = ((const float4*)x)[threadIdx.x];
    float s = v.x + v.y + v.z + v.w;
    float ss = v.x * v.x + v.y * v.y + v.z * v.z + v.w * v.w;
#pragma unroll
    for (int o = 32; o > 0; o >>= 1) { s += __shfl_xor(s, o); ss += __shfl_xor(ss, o); }
    __shared__ float sa[4], sb[4];
    int wv = threadIdx.x >> 6;
    if ((threadIdx.x & 63) == 0) { sa[wv] = s; sb[wv] = ss; }
    __syncthreads();
    s = sa[0] + sa[1] + sa[2] + sa[3];
    ss = sb[0] + sb[1] + sb[2] + sb[3];
    float mean = s * (1.f / 1024.f);
    float var = ss * (1.f / 1024.f) - mean * mean;
    float r = rsqrtf(var + 1e-6f);
    int c = threadIdx.x << 2;
    float t0 = (v.x - mean) * r, t1 = (v.y - mean) * r, t2 = (v.z - mean) * r, t3 = (v.w - mean) * r;
    float o0, o1, o2, o3;
    if (mode == 0) { o0 = t0; o1 = t1; o2 = t2; o3 = t3; }
    else if (mode == 1) {
        o0 = t0 * (1.f + w[c]) + b[c];
        o1 = t1 * (1.f + w[c + 1]) + b[c + 1];
        o2 = t2 * (1.f + w[c + 2]) + b[c + 2];
        o3 = t3 * (1.f + w[c + 3]) + b[c + 3];
    } else {
        o0 = t0 * w[c] + b[c];
        o1 = t1 * w[c + 1] + b[c + 1];
        o2 = t2 * w[c + 2] + b[c + 2];
        o3 = t3 * w[c + 3] + b[c + 3];
    }
    union { u16 u[4]; us4 v4; } pk;
    pk.u[0] = f2b(o0); pk.u[1] = f2b(o1); pk.u[2] = f2b(o2); pk.u[3] = f2b(o3);
    ((us4*)(Y + (size_t)row * CDIM))[threadIdx.x] = pk.v4;
}

// ---------------- weight transpose + fp32->bf16: W[K][N] -> Wt[N][K] ----------------
__global__ __launch_bounds__(256) void wtrans_kernel(const float* __restrict__ W, u16* __restrict__ Wt,
                                                     int K, int N) {
    __shared__ u16 s[64 * 72];
    int n0 = blockIdx.x * 64, k0 = blockIdx.y * 64;
    int t = threadIdx.x;
    int kk = t >> 4, n4 = (t & 15) * 4;
#pragma unroll
    for (int i = 0; i < 4; ++i) {
        int k = kk + i * 16;
        float4 w4 = *(const float4*)(W + (size_t)(k0 + k) * N + n0 + n4);
        s[(n4 + 0) * 72 + k] = f2b(w4.x);
        s[(n4 + 1) * 72 + k] = f2b(w4.y);
        s[(n4 + 2) * 72 + k] = f2b(w4.z);
        s[(n4 + 3) * 72 + k] = f2b(w4.w);
    }
    __syncthreads();
    int n = t >> 2, kh = (t & 3) * 16;
    u16* dst = Wt + (size_t)(n0 + n) * K + k0 + kh;
    *(us8*)dst = *(const us8*)&s[n * 72 + kh];
    *(us8*)(dst + 8) = *(const us8*)&s[n * 72 + kh + 8];
}

// fp32 -> bf16 elementwise
__global__ void cvt_kernel(const float* __restrict__ src, u16* __restrict__ dst, int n) {
    int i = blockIdx.x * 256 + threadIdx.x;
    if (i < n) dst[i] = f2b(src[i]);
}

// ---------------- bf16 MFMA GEMM: C[M,N] = A[M,K] @ B[K,N](as Bt[N][K]) + bias ----------------
// 128x128 tile, BK=32, 256 threads = 4 waves (2x2), each wave 64x64.
// Staging: global_load_lds width=16, linear LDS [128][32], chunk-XOR swizzle on the
// SOURCE address (LDS chunk (r,c) holds global chunk (r, c^(r&3))), double-buffered
// with raw s_barrier + counted vmcnt(4) so next K-tile loads fly under current MFMA.
__global__ __launch_bounds__(256) void bgemm_kernel(const u16* __restrict__ A, int lda,
                                                    const u16* __restrict__ Bt, int ldbt,
                                                    float* __restrict__ C, u16* __restrict__ Cb, int ldc,
                                                    int M, int N, int K,
                                                    const float* __restrict__ bias, int act) {
    __shared__ __align__(16) u16 As[2][128 * 32];
    __shared__ __align__(16) u16 Bs[2][128 * 32];
    int t = threadIdx.x;
    int w = t >> 6, lane = t & 63, quad = lane >> 4, l15 = lane & 15;
    int wm = w & 1, wn = w >> 1;
    int m0 = blockIdx.y * 128, n0 = blockIdx.x * 128;
    // staging geometry: thread t covers LDS chunks t and t+256 (16B each)
    int r = t >> 2;
    int scol = (t & 3) ^ (r & 3);
    int ar0 = m0 + r; if (ar0 >= M) ar0 = M - 1;
    int ar1 = m0 + r + 64; if (ar1 >= M) ar1 = M - 1;
    const u16* apA0 = A + (size_t)ar0 * lda + scol * 8;
    const u16* apA1 = A + (size_t)ar1 * lda + scol * 8;
    const u16* bp0 = Bt + (size_t)(n0 + r) * ldbt + scol * 8;
    const u16* bp1 = Bt + (size_t)(n0 + r + 64) * ldbt + scol * 8;
    int ldsb = w << 9;                       // wave-uniform dest base (u16); +lane*16B by HW
    f32x4 acc[4][4];
#pragma unroll
    for (int i = 0; i < 4; ++i)
#pragma unroll
        for (int j = 0; j < 4; ++j) acc[i][j] = (f32x4){0.f, 0.f, 0.f, 0.f};
    int ksw = quad ^ (l15 & 3);              // swizzled chunk for fragment reads
    int nkt = K >> 5;
    gload16(apA0, &As[0][ldsb]);
    gload16(apA1, &As[0][2048 + ldsb]);
    gload16(bp0, &Bs[0][ldsb]);
    gload16(bp1, &Bs[0][2048 + ldsb]);
    for (int tt = 0; tt < nkt; ++tt) {
        int b = tt & 1;
        if (tt + 1 < nkt) {
            int k0 = (tt + 1) << 5;
            gload16(apA0 + k0, &As[b ^ 1][ldsb]);
            gload16(apA1 + k0, &As[b ^ 1][2048 + ldsb]);
            gload16(bp0 + k0, &Bs[b ^ 1][ldsb]);
            gload16(bp1 + k0, &Bs[b ^ 1][2048 + ldsb]);
            asm volatile("s_waitcnt vmcnt(4)" ::: "memory");   // tile tt landed; tt+1 in flight
        } else {
            asm volatile("s_waitcnt vmcnt(0)" ::: "memory");
        }
        __builtin_amdgcn_s_barrier();
        const u16* as = As[b];
        const u16* bs = Bs[b];
        bf16x8 af[4], bfr[4];
#pragma unroll
        for (int mt = 0; mt < 4; ++mt)
            af[mt] = *(const bf16x8*)(as + ((wm * 64 + mt * 16 + l15) << 5) + (ksw << 3));
#pragma unroll
        for (int nt = 0; nt < 4; ++nt)
            bfr[nt] = *(const bf16x8*)(bs + ((wn * 64 + nt * 16 + l15) << 5) + (ksw << 3));
#pragma unroll
        for (int mt = 0; mt < 4; ++mt)
#pragma unroll
            for (int nt = 0; nt < 4; ++nt)
                acc[mt][nt] = __builtin_amdgcn_mfma_f32_16x16x32_bf16(af[mt], bfr[nt], acc[mt][nt], 0, 0, 0);
        __builtin_amdgcn_s_barrier();
    }
#pragma unroll
    for (int nt = 0; nt < 4; ++nt) {
        int ncol = n0 + wn * 64 + nt * 16 + l15;
        float bv = bias[ncol];
#pragma unroll
        for (int mt = 0; mt < 4; ++mt) {
#pragma unroll
            for (int rr = 0; rr < 4; ++rr) {
                int row = m0 + wm * 64 + mt * 16 + quad * 4 + rr;
                if (row < M) {
                    float v = acc[mt][nt][rr] + bv;
                    if (act) v = gelu_f(v);
                    if (Cb) Cb[(size_t)row * ldc + ncol] = f2b(v);
                    else C[(size_t)row * ldc + ncol] = v;
                }
            }
        }
    }
}

// ---------------- RMS-norm * gamma on q slice of qkv buffer (fp32, in place) ----------------
__global__ void rmsq_kernel(float* __restrict__ qkv, const float* __restrict__ qg, int S) {
    int gid = blockIdx.x * blockDim.x + threadIdx.x;
    int wid = gid >> 6;
    int lane = gid & 63;
    if (wid >= S * 16) return;
    int s = wid >> 4, hh = wid & 15;
    float* p = qkv + (size_t)s * 3072 + hh * 64 + lane;
    float v = *p;
    float sq = v * v;
#pragma unroll
    for (int o = 32; o > 0; o >>= 1) sq += __shfl_xor(sq, o);
    float r = rsqrtf(sq * (1.f / 64.f) + 1e-6f);
    *p = v * r * qg[hh * 64 + lane];
}

// ---------------- K prep: fp32 rows (stride ld) -> bf16 Kb[h][Skpad][64], optional rms*gamma
__global__ void kprep_kernel(const float* __restrict__ K, int ld, u16* __restrict__ Kb,
                             int Sk, int Skpad, const float* __restrict__ gamma) {
    int v = threadIdx.x >> 6, lane = threadIdx.x & 63;
    int s = blockIdx.x * 4 + v;
    int h = blockIdx.y;
    if (s >= Skpad) return;
    u16* dst = Kb + ((size_t)h * Skpad + s) * 64 + lane;
    if (s >= Sk) { *dst = 0; return; }
    float x = K[(size_t)s * ld + h * 64 + lane];
    if (gamma) {
        float sq = x * x;
#pragma unroll
        for (int o = 32; o > 0; o >>= 1) sq += __shfl_xor(sq, o);
        x = x * rsqrtf(sq * (1.f / 64.f) + 1e-6f) * gamma[h * 64 + lane];
    }
    *dst = f2b(x);
}

// ---------------- V prep: transpose per head -> bf16 Vt[h][64][Skpad]
__global__ __launch_bounds__(256) void vtprep_kernel(const float* __restrict__ V, int ld,
                                                     u16* __restrict__ Vt, int Sk, int Skpad) {
    __shared__ __align__(16) u16 s[64 * 72];
    int h = blockIdx.y;
    int k0 = blockIdx.x * 64;
    int t = threadIdx.x;
    int kk = t >> 4, d4 = (t & 15) * 4;
#pragma unroll
    for (int i = 0; i < 4; ++i) {
        int k = kk + i * 16;
        float4 v4 = make_float4(0.f, 0.f, 0.f, 0.f);
        if (k0 + k < Sk) v4 = *(const float4*)(V + (size_t)(k0 + k) * ld + h * 64 + d4);
        s[(d4 + 0) * 72 + k] = f2b(v4.x);
        s[(d4 + 1) * 72 + k] = f2b(v4.y);
        s[(d4 + 2) * 72 + k] = f2b(v4.z);
        s[(d4 + 3) * 72 + k] = f2b(v4.w);
    }
    __syncthreads();
    int d = t >> 2, kh = (t & 3) * 16;
    u16* dst = Vt + ((size_t)h * 64 + d) * Skpad + k0 + kh;
    *(us8*)dst = *(const us8*)&s[d * 72 + kh];
    *(us8*)(dst + 8) = *(const us8*)&s[d * 72 + kh + 8];
}

// ---------------- MFMA flash attention v2 ----------------
__global__ __launch_bounds__(256) void attn2_kernel(const float* __restrict__ Q, int qs,
                                                    const u16* __restrict__ Kb,
                                                    const u16* __restrict__ Vt,
                                                    int Skpad,
                                                    u16* __restrict__ O, int os,
                                                    int Sq, int Sk, int nqb) {
    __shared__ __align__(16) u16 sK2[2][64 * 64];
    __shared__ __align__(16) u16 sV2[2][64 * 64];
    __shared__ __align__(16) u16 sP[64 * 64];
    int nwg = nqb * 16;
    int cpx = nwg >> 3;                       // nwg % 8 == 0
    int bid = blockIdx.x;
    int gid = (bid & 7) * cpx + (bid >> 3);
    int hh = gid / nqb;
    int q0 = (gid - hh * nqb) * 64;
    int t = threadIdx.x;
    int w = t >> 6, lane = t & 63, quad = lane >> 4, l15 = lane & 15;
    const u16* KH = Kb + (size_t)hh * Skpad * 64;
    const u16* VH = Vt + (size_t)hh * 64 * Skpad;
    int qrow = q0 + w * 16 + l15; if (qrow >= Sq) qrow = Sq - 1;
    const float* qp = Q + (size_t)qrow * qs + hh * 64 + quad * 8;
    bf16x8 bq[2];
#pragma unroll
    for (int c = 0; c < 2; ++c) {
        float4 x = *(const float4*)(qp + c * 32);
        float4 y = *(const float4*)(qp + c * 32 + 4);
        union { u16 u[8]; bf16x8 v; } pk;
        pk.u[0] = f2b(x.x * 0.125f); pk.u[1] = f2b(x.y * 0.125f);
        pk.u[2] = f2b(x.z * 0.125f); pk.u[3] = f2b(x.w * 0.125f);
        pk.u[4] = f2b(y.x * 0.125f); pk.u[5] = f2b(y.y * 0.125f);
        pk.u[6] = f2b(y.z * 0.125f); pk.u[7] = f2b(y.w * 0.125f);
        bq[c] = pk.v;
    }
    float m_run = -3e38f, l_run = 0.f;
    f32x4 oacc[4];
#pragma unroll
    for (int j = 0; j < 4; ++j) oacc[j] = (f32x4){0.f, 0.f, 0.f, 0.f};

    int r0 = t >> 3;
    int c0 = (t & 7) ^ (r0 & 7);
    int ldsc = (t & 192) << 3;

    auto STAGE = [&](u16* skb, u16* svb, int k0) {
        const u16* gk0 = KH + ((size_t)(k0 + r0) << 6) + (c0 << 3);
        const u16* gk1 = KH + ((size_t)(k0 + r0 + 32) << 6) + (c0 << 3);
        const u16* gv0 = VH + (size_t)r0 * Skpad + k0 + (c0 << 3);
        const u16* gv1 = VH + (size_t)(r0 + 32) * Skpad + k0 + (c0 << 3);
        gload16(gk0, skb + ldsc);
        gload16(gv0, svb + ldsc);
        gload16(gk1, skb + 2048 + ldsc);
        gload16(gv1, svb + 2048 + ldsc);
    };

    int ntile = Skpad >> 6;
    STAGE(sK2[0], sV2[0], 0);
    for (int tt = 0; tt < ntile; ++tt) {
        int k0 = tt << 6;
        int b = tt & 1;
        if (tt + 1 < ntile) {
            STAGE(sK2[b ^ 1], sV2[b ^ 1], k0 + 64);
            asm volatile("s_waitcnt vmcnt(4)" ::: "memory");
        } else {
            asm volatile("s_waitcnt vmcnt(0)" ::: "memory");
        }
        __builtin_amdgcn_s_barrier();
        const u16* sk = sK2[b];
        const u16* sv = sV2[b];
        f32x4 sc[4];
#pragma unroll
        for (int mt = 0; mt < 4; ++mt) {
            int row = mt * 16 + l15;
            int sw = row & 7;
            bf16x8 a0 = *(const bf16x8*)(sk + (((row << 3) | (quad ^ sw)) << 3));
            bf16x8 a1 = *(const bf16x8*)(sk + (((row << 3) | ((4 | quad) ^ sw)) << 3));
            f32x4 z = (f32x4){0.f, 0.f, 0.f, 0.f};
            z = __builtin_amdgcn_mfma_f32_16x16x32_bf16(a0, bq[0], z, 0, 0, 0);
            z = __builtin_amdgcn_mfma_f32_16x16x32_bf16(a1, bq[1], z, 0, 0, 0);
            sc[mt] = z;
        }
        if (k0 + 64 > Sk) {
#pragma unroll
            for (int mt = 0; mt < 4; ++mt)
#pragma unroll
                for (int r = 0; r < 4; ++r)
                    if (k0 + mt * 16 + quad * 4 + r >= Sk) sc[mt][r] = -3e38f;
        }
        float mx = -3e38f;
#pragma unroll
        for (int mt = 0; mt < 4; ++mt)
#pragma unroll
            for (int r = 0; r < 4; ++r) mx = fmaxf(mx, sc[mt][r]);
        mx = fmaxf(mx, __shfl_xor(mx, 16));
        mx = fmaxf(mx, __shfl_xor(mx, 32));
        float mn = fmaxf(m_run, mx);
        float alpha = __expf(m_run - mn);
        float ls = 0.f;
#pragma unroll
        for (int mt = 0; mt < 4; ++mt)
#pragma unroll
            for (int r = 0; r < 4; ++r) {
                float p = __expf(sc[mt][r] - mn);
                sc[mt][r] = p;
                ls += p;
            }
        ls += __shfl_xor(ls, 16);
        ls += __shfl_xor(ls, 32);
        l_run = l_run * alpha + ls;
        m_run = mn;
#pragma unroll
        for (int mt = 0; mt < 4; ++mt) {
            union { u16 u[4]; us4 v; } pk;
            pk.u[0] = f2b(sc[mt][0]); pk.u[1] = f2b(sc[mt][1]);
            pk.u[2] = f2b(sc[mt][2]); pk.u[3] = f2b(sc[mt][3]);
            int pch = (mt * 2 + (quad >> 1)) ^ (l15 & 7);
            *(us4*)&sP[(w * 16 + l15) * 64 + pch * 8 + (quad & 1) * 4] = pk.v;
        }
        float alr[4];
#pragma unroll
        for (int r = 0; r < 4; ++r) alr[r] = __shfl(alpha, (lane & 48) | (quad * 4 + r));
#pragma unroll
        for (int j = 0; j < 4; ++j)
#pragma unroll
            for (int r = 0; r < 4; ++r) oacc[j][r] *= alr[r];
#pragma unroll
        for (int c = 0; c < 2; ++c) {
            bf16x8 pa = *(const bf16x8*)&sP[(w * 16 + l15) * 64 + ((((c << 2) | quad) ^ (l15 & 7)) << 3)];
#pragma unroll
            for (int n2 = 0; n2 < 4; ++n2) {
                int row = n2 * 16 + l15;
                int ch = ((c << 2) | quad) ^ (row & 7);
                bf16x8 vb = *(const bf16x8*)(sv + (((row << 3) | ch) << 3));
                oacc[n2] = __builtin_amdgcn_mfma_f32_16x16x32_bf16(pa, vb, oacc[n2], 0, 0, 0);
            }
        }
        __builtin_amdgcn_s_barrier();
        asm volatile("" ::: "memory");
    }
    float lr[4];
#pragma unroll
    for (int r = 0; r < 4; ++r) lr[r] = __shfl(l_run, (lane & 48) | (quad * 4 + r));
#pragma unroll
    for (int r = 0; r < 4; ++r) {
        int q = q0 + w * 16 + quad * 4 + r;
        if (q < Sq) {
            float inv = 1.f / lr[r];
#pragma unroll
            for (int j = 0; j < 4; ++j)
                O[(size_t)q * os + hh * 64 + j * 16 + l15] = f2b(oacc[j][r] * inv);
        }
    }
}

// h += (g ? g[c]* : 1*) p
__global__ void resid_kernel(float* __restrict__ h, const float* __restrict__ p,
                             const float* __restrict__ g, int n4) {
    int i = blockIdx.x * 256 + threadIdx.x;
    if (i >= n4) return;
    float4 hv = ((float4*)h)[i];
    float4 pv = ((const float4*)p)[i];
    if (g) {
        int c = (i & 255) << 2;
        hv.x += g[c] * pv.x;
        hv.y += g[c + 1] * pv.y;
        hv.z += g[c + 2] * pv.z;
        hv.w += g[c + 3] * pv.w;
    } else {
        hv.x += pv.x; hv.y += pv.y; hv.z += pv.z; hv.w += pv.w;
    }
    ((float4*)h)[i] = hv;
}

// out[c][l] = hn_bf16[5+l] . out_w[:,c] + out_b[c]; wave per row l, shuffle-reduce
__global__ __launch_bounds__(256) void out_kernel(const u16* __restrict__ hn, const float* __restrict__ out_w,
                                                  const float* __restrict__ out_b, float* __restrict__ out) {
    int w = threadIdx.x >> 6, lane = threadIdx.x & 63;
    int l = blockIdx.x * 4 + w;
    const u16* row = hn + (size_t)(5 + l) * CDIM;
    float acc[8] = {0.f, 0.f, 0.f, 0.f, 0.f, 0.f, 0.f, 0.f};
#pragma unroll
    for (int i = 0; i < 16; ++i) {
        int k = i * 64 + lane;
        float hv = b2f(row[k]);
        float4 w0 = *(const float4*)(out_w + k * 8);
        float4 w1 = *(const float4*)(out_w + k * 8 + 4);
        acc[0] = fmaf(hv, w0.x, acc[0]); acc[1] = fmaf(hv, w0.y, acc[1]);
        acc[2] = fmaf(hv, w0.z, acc[2]); acc[3] = fmaf(hv, w0.w, acc[3]);
        acc[4] = fmaf(hv, w1.x, acc[4]); acc[5] = fmaf(hv, w1.y, acc[5]);
        acc[6] = fmaf(hv, w1.z, acc[6]); acc[7] = fmaf(hv, w1.w, acc[7]);
    }
#pragma unroll
    for (int c = 0; c < 8; ++c) {
        float a = acc[c];
#pragma unroll
        for (int o = 32; o > 0; o >>= 1) a += __shfl_xor(a, o);
        if (lane == c) out[c * 4096 + l] = a + out_b[c];
    }
}

extern "C" void kernel_launch(void* const* d_in, const int* in_sizes, int n_in,
                              void* d_out, int out_size, void* d_ws, size_t ws_size,
                              hipStream_t stream) {
    const float* x        = (const float*)d_in[0];
    const float* t        = (const float*)d_in[1];
    const float* cond     = (const float*)d_in[2];
    const float* t_w1     = (const float*)d_in[3];
    const float* t_b1     = (const float*)d_in[4];
    const float* t_w2     = (const float*)d_in[5];
    const float* t_b2     = (const float*)d_in[6];
    const float* in_w     = (const float*)d_in[7];
    const float* in_b     = (const float*)d_in[8];
    const float* pos_tok  = (const float*)d_in[9];
    const float* reg_tok  = (const float*)d_in[10];
    const float* ada_w    = (const float*)d_in[11];
    const float* ada_b    = (const float*)d_in[12];
    const float* qkv_w    = (const float*)d_in[13];
    const float* qkv_b    = (const float*)d_in[14];
    const float* q_gamma  = (const float*)d_in[15];
    const float* k_gamma  = (const float*)d_in[16];
    const float* attn_ow  = (const float*)d_in[17];
    const float* attn_ob  = (const float*)d_in[18];
    const float* n2_w     = (const float*)d_in[19];
    const float* n2_b     = (const float*)d_in[20];
    const float* cq_w     = (const float*)d_in[21];
    const float* cq_b     = (const float*)d_in[22];
    const float* ckv_w    = (const float*)d_in[23];
    const float* ckv_b    = (const float*)d_in[24];
    const float* co_w     = (const float*)d_in[25];
    const float* co_b     = (const float*)d_in[26];
    const float* mlp_w1   = (const float*)d_in[27];
    const float* mlp_b1   = (const float*)d_in[28];
    const float* mlp_w2   = (const float*)d_in[29];
    const float* mlp_b2   = (const float*)d_in[30];
    const float* out_w    = (const float*)d_in[31];
    const float* out_b    = (const float*)d_in[32];

    const int S = S_TOK;
    const size_t SC = (size_t)S * 1024;
    float* ws = (float*)d_ws;
    float* h    = ws;                    // S*1024 fp32
    float* F    = h + SC;                // S*1024 fp32
    float* D    = F + SC;                // S*4096 fp32 (also: q | kv | ff1-bf16)
    float* tf   = D + SC * 4;
    float* s1   = tf + 256;
    float* stemb = s1 + 1024;
    float* mod  = stemb + 1024;          // 4*6144
    float* part = mod + 4 * 6144;        // 16*24576
    float* fend = part + 16 * 24576;
    u16* hn    = (u16*)fend;             // S*1024 bf16
    u16* E     = hn + SC;                // S*1024 bf16
    u16* condb = E + SC;                 // 1M bf16
    u16* wt    = condb + 1024 * 1024;
    u16* wt_qkv = wt;
    u16* wt_o   = wt_qkv + (size_t)1024 * 3072;
    u16* wt_cq  = wt_o   + (size_t)1024 * 1024;
    u16* wt_ckv = wt_cq  + (size_t)1024 * 1024;
    u16* wt_co  = wt_ckv + (size_t)1024 * 2048;
    u16* wt_m1  = wt_co  + (size_t)1024 * 1024;
    u16* wt_m2  = wt_m1  + (size_t)1024 * 4096;
    u16* Kb     = wt_m2  + (size_t)4096 * 1024;          // 16*4160*64 bf16
    u16* Vt     = Kb + (size_t)16 * SKPAD_SELF * 64;     // 16*4160*64 bf16
    float* q_buf = D;                    // cross-attn q (S*1024 fp32)
    float* kv    = D + SC;               // 1024*2048 fp32
    u16* ff1     = (u16*)D;              // S*4096 bf16

    // temb / adaLN modulation chain (split-K parallel)
    tfreq_kernel<<<1, 256, 0, stream>>>(t, tf);
    gemvp_kernel<<<dim3(4, 8), 256, 0, stream>>>(tf, t_w1, 1024, part, 32, 1024);
    gemvr_kernel<<<4, 256, 0, stream>>>(part, t_b1, s1, 1024, 8, 1);
    gemvp_kernel<<<dim3(4, 16), 256, 0, stream>>>(s1, t_w2, 1024, part, 64, 1024);
    gemvr_kernel<<<4, 256, 0, stream>>>(part, t_b2, stemb, 1024, 16, 1);  // stemb = silu(temb)
    modp_kernel<<<dim3(96, 16), 256, 0, stream>>>(stemb, ada_w, part);
    modr_kernel<<<96, 256, 0, stream>>>(part, ada_b, mod);

    // input embed + cond bf16
    embed_kernel<<<(S * 1024 + 255) / 256, 256, 0, stream>>>(x, in_w, in_b, pos_tok, reg_tok, h);
    cvt_kernel<<<4096, 256, 0, stream>>>(cond, condb, 1024 * 1024);

    int gy = (S + 127) / 128;   // 33
    int nqb = (S + 63) / 64;    // 65
    int nwg = nqb * 16;         // 1040 (divisible by 8)
    for (int i = 0; i < 4; ++i) {
        const float* modb = mod + i * 6144;
        // weight prep (transpose + bf16)
        wtrans_kernel<<<dim3(3072 / 64, 16), 256, 0, stream>>>(qkv_w + (size_t)i * 1024 * 3072, wt_qkv, 1024, 3072);
        wtrans_kernel<<<dim3(16, 16), 256, 0, stream>>>(attn_ow + (size_t)i * 1024 * 1024, wt_o, 1024, 1024);
        wtrans_kernel<<<dim3(16, 16), 256, 0, stream>>>(cq_w + (size_t)i * 1024 * 1024, wt_cq, 1024, 1024);
        wtrans_kernel<<<dim3(32, 16), 256, 0, stream>>>(ckv_w + (size_t)i * 1024 * 2048, wt_ckv, 1024, 2048);
        wtrans_kernel<<<dim3(16, 16), 256, 0, stream>>>(co_w + (size_t)i * 1024 * 1024, wt_co, 1024, 1024);
        wtrans_kernel<<<dim3(64, 16), 256, 0, stream>>>(mlp_w1 + (size_t)i * 1024 * 4096, wt_m1, 1024, 4096);
        wtrans_kernel<<<dim3(16, 64), 256, 0, stream>>>(mlp_w2 + (size_t)i * 4096 * 1024, wt_m2, 4096, 1024);

        // hn = ln(h)*(1+sc1)+sh1  (bf16)
        ln_kernel<<<S, 256, 0, stream>>>(h, hn, modb + 1024, modb + 0, 1);
        // qkv = hn @ qkv_w + b  (fp32 out)
        bgemm_kernel<<<dim3(24, gy), 256, 0, stream>>>(hn, 1024, wt_qkv, 1024, D, nullptr, 3072,
                                                       S, 3072, 1024, qkv_b + i * 3072, 0);
        // q-rms in place; k-rms fused into kprep; V transposed once per layer
        rmsq_kernel<<<(S * 16 * 64 + 255) / 256, 256, 0, stream>>>(D, q_gamma + i * 1024, S);
        kprep_kernel<<<dim3(SKPAD_SELF / 4, 16), 256, 0, stream>>>(D + 1024, 3072, Kb, S, SKPAD_SELF, k_gamma + i * 1024);
        vtprep_kernel<<<dim3(SKPAD_SELF / 64, 16), 256, 0, stream>>>(D + 2048, 3072, Vt, S, SKPAD_SELF);
        // self attention -> E (bf16)
        attn2_kernel<<<nwg, 256, 0, stream>>>(D, 3072, Kb, Vt, SKPAD_SELF, E, 1024, S, S, nqb);
        // o-proj
        bgemm_kernel<<<dim3(8, gy), 256, 0, stream>>>(E, 1024, wt_o, 1024, F, nullptr, 1024,
                                                      S, 1024, 1024, attn_ob + i * 1024, 0);
        resid_kernel<<<S, 256, 0, stream>>>(h, F, modb + 2 * 1024, S * 256);

        // hn = ln(h, n2_w, n2_b)
        ln_kernel<<<S, 256, 0, stream>>>(h, hn, n2_w + i * 1024, n2_b + i * 1024, 2);
        // q = hn @ cq_w
        bgemm_kernel<<<dim3(8, gy), 256, 0, stream>>>(hn, 1024, wt_cq, 1024, q_buf, nullptr, 1024,
                                                      S, 1024, 1024, cq_b + i * 1024, 0);
        // kv = cond @ ckv_w
        bgemm_kernel<<<dim3(16, 8), 256, 0, stream>>>(condb, 1024, wt_ckv, 1024, kv, nullptr, 2048,
                                                      1024, 2048, 1024, ckv_b + i * 2048, 0);
        // cross-attn prep (no rms) + attention -> E
        kprep_kernel<<<dim3(1024 / 4, 16), 256, 0, stream>>>(kv, 2048, Kb, 1024, 1024, nullptr);
        vtprep_kernel<<<dim3(1024 / 64, 16), 256, 0, stream>>>(kv + 1024, 2048, Vt, 1024, 1024);
        attn2_kernel<<<nwg, 256, 0, stream>>>(q_buf, 1024, Kb, Vt, 1024, E, 1024, S, 1024, nqb);
        // co proj
        bgemm_kernel<<<dim3(8, gy), 256, 0, stream>>>(E, 1024, wt_co, 1024, F, nullptr, 1024,
                                                      S, 1024, 1024, co_b + i * 1024, 0);
        resid_kernel<<<S, 256, 0, stream>>>(h, F, nullptr, S * 256);

        // hn = ln(h)*(1+sc2)+sh2
        ln_kernel<<<S, 256, 0, stream>>>(h, hn, modb + 4 * 1024, modb + 3 * 1024, 1);
        // ff1 = gelu(hn @ mlp_w1 + b1)  (bf16 out)
        bgemm_kernel<<<dim3(32, gy), 256, 0, stream>>>(hn, 1024, wt_m1, 1024, nullptr, ff1, 4096,
                                                       S, 4096, 1024, mlp_b1 + i * 4096, 1);
        // ff2 = ff1 @ mlp_w2 + b2
        bgemm_kernel<<<dim3(8, gy), 256, 0, stream>>>(ff1, 4096, wt_m2, 4096, F, nullptr, 1024,
                                                      S, 1024, 4096, mlp_b2 + i * 1024, 0);
        resid_kernel<<<S, 256, 0, stream>>>(h, F, modb + 5 * 1024, S * 256);
    }
    // final LN + out proj + transpose
    ln_kernel<<<S, 256, 0, stream>>>(h, hn, nullptr, nullptr, 0);
    out_kernel<<<1024, 256, 0, stream>>>(hn, out_w, out_b, (float*)d_out);
}